// Round 2
// baseline (6033.263 us; speedup 1.0000x reference)
//
#include <hip/hip_runtime.h>
#include <hip/hip_bf16.h>

// VanillaRNN on MI355X.
// h_{t} = tanh(x_t @ W_hx^T + h_{t-1} @ W_hh^T + b_hx + b_hh)   (hh term skipped at t=0)
// out   = h_last @ W_out^T + b_out
//
// Strategy: fuse input projection into the step GEMM as extra K (K = 2048 + 512).
// bf16 MFMA 16x16x32, fp32 accum, fragments loaded directly from global (NT layout,
// both operands K-contiguous -> 16B/lane loads). W converted to bf16 once per launch.

#define BB 256
#define SS 128
#define II 512
#define HH 2048
#define OO 10

typedef __attribute__((ext_vector_type(8))) __bf16 bf16x8;
typedef __attribute__((ext_vector_type(4))) __bf16 bf16x4;
typedef __attribute__((ext_vector_type(4))) float f32x4;

__global__ __launch_bounds__(256) void cvt_f32_bf16(const float* __restrict__ in,
                                                    __bf16* __restrict__ out, int n4) {
    int stride = gridDim.x * blockDim.x;
    for (int i = blockIdx.x * blockDim.x + threadIdx.x; i < n4; i += stride) {
        float4 v = reinterpret_cast<const float4*>(in)[i];
        bf16x4 o;
        o[0] = (__bf16)v.x; o[1] = (__bf16)v.y; o[2] = (__bf16)v.z; o[3] = (__bf16)v.w;
        *reinterpret_cast<bf16x4*>(out + 4 * (size_t)i) = o;
    }
}

// One recurrence step. Grid: (B/64, H/64); block: 256 threads = 4 waves (2x2),
// each wave computes a 32x32 output tile as 2x2 MFMA fragments.
__global__ __launch_bounds__(256) void rnn_step(
    const __bf16* __restrict__ h_in,   // [B][H] bf16, ignored if has_h==0
    const float*  __restrict__ x,      // [B][S][I] fp32
    int t,
    const __bf16* __restrict__ Whh,    // [H][H] bf16
    const __bf16* __restrict__ Whx,    // [H][I] bf16
    const float*  __restrict__ b_hx,   // [H]
    const float*  __restrict__ b_hh,   // [H]
    __bf16* __restrict__ h_out,        // [B][H] bf16
    int has_h)
{
    const int tid  = threadIdx.x;
    const int lane = tid & 63;
    const int wid  = tid >> 6;
    const int wm   = wid >> 1;          // 0..1
    const int wn   = wid & 1;           // 0..1
    const int row0 = blockIdx.x * 64 + wm * 32;   // batch rows
    const int col0 = blockIdx.y * 64 + wn * 32;   // hidden cols
    const int lr   = lane & 15;         // fragment row/col index
    const int lk   = (lane >> 4) * 8;   // fragment k offset (contiguous 8)

    f32x4 acc[2][2] = {};

    if (has_h) {
        const __bf16* a0p = h_in + (size_t)(row0 + lr) * HH + lk;
        const __bf16* a1p = a0p + (size_t)16 * HH;
        const __bf16* b0p = Whh + (size_t)(col0 + lr) * HH + lk;
        const __bf16* b1p = b0p + (size_t)16 * HH;
#pragma unroll 4
        for (int k = 0; k < HH; k += 32) {
            bf16x8 a0 = *reinterpret_cast<const bf16x8*>(a0p + k);
            bf16x8 a1 = *reinterpret_cast<const bf16x8*>(a1p + k);
            bf16x8 b0 = *reinterpret_cast<const bf16x8*>(b0p + k);
            bf16x8 b1 = *reinterpret_cast<const bf16x8*>(b1p + k);
            acc[0][0] = __builtin_amdgcn_mfma_f32_16x16x32_bf16(a0, b0, acc[0][0], 0, 0, 0);
            acc[0][1] = __builtin_amdgcn_mfma_f32_16x16x32_bf16(a0, b1, acc[0][1], 0, 0, 0);
            acc[1][0] = __builtin_amdgcn_mfma_f32_16x16x32_bf16(a1, b0, acc[1][0], 0, 0, 0);
            acc[1][1] = __builtin_amdgcn_mfma_f32_16x16x32_bf16(a1, b1, acc[1][1], 0, 0, 0);
        }
    }

    // Input-projection part: A rows come from x[b][t][:] (fp32, converted on the fly).
    {
        const float* ax0 = x + ((size_t)(row0 + lr) * SS + t) * II + lk;
        const float* ax1 = ax0 + (size_t)16 * SS * II;
        const __bf16* b0p = Whx + (size_t)(col0 + lr) * II + lk;
        const __bf16* b1p = b0p + (size_t)16 * II;
#pragma unroll 4
        for (int k = 0; k < II; k += 32) {
            float4 f0 = *reinterpret_cast<const float4*>(ax0 + k);
            float4 f1 = *reinterpret_cast<const float4*>(ax0 + k + 4);
            float4 g0 = *reinterpret_cast<const float4*>(ax1 + k);
            float4 g1 = *reinterpret_cast<const float4*>(ax1 + k + 4);
            bf16x8 a0, a1;
            a0[0] = (__bf16)f0.x; a0[1] = (__bf16)f0.y; a0[2] = (__bf16)f0.z; a0[3] = (__bf16)f0.w;
            a0[4] = (__bf16)f1.x; a0[5] = (__bf16)f1.y; a0[6] = (__bf16)f1.z; a0[7] = (__bf16)f1.w;
            a1[0] = (__bf16)g0.x; a1[1] = (__bf16)g0.y; a1[2] = (__bf16)g0.z; a1[3] = (__bf16)g0.w;
            a1[4] = (__bf16)g1.x; a1[5] = (__bf16)g1.y; a1[6] = (__bf16)g1.z; a1[7] = (__bf16)g1.w;
            bf16x8 b0 = *reinterpret_cast<const bf16x8*>(b0p + k);
            bf16x8 b1 = *reinterpret_cast<const bf16x8*>(b1p + k);
            acc[0][0] = __builtin_amdgcn_mfma_f32_16x16x32_bf16(a0, b0, acc[0][0], 0, 0, 0);
            acc[0][1] = __builtin_amdgcn_mfma_f32_16x16x32_bf16(a0, b1, acc[0][1], 0, 0, 0);
            acc[1][0] = __builtin_amdgcn_mfma_f32_16x16x32_bf16(a1, b0, acc[1][0], 0, 0, 0);
            acc[1][1] = __builtin_amdgcn_mfma_f32_16x16x32_bf16(a1, b1, acc[1][1], 0, 0, 0);
        }
    }

    // Epilogue: D mapping (verified): col = lane&15, row = 4*(lane>>4) + reg.
    const int hr = (lane >> 4) * 4;
#pragma unroll
    for (int i = 0; i < 2; ++i) {
#pragma unroll
        for (int j = 0; j < 2; ++j) {
            const int col = col0 + j * 16 + lr;
            const float bias = b_hx[col] + (has_h ? b_hh[col] : 0.0f);
#pragma unroll
            for (int r = 0; r < 4; ++r) {
                const int row = row0 + i * 16 + hr + r;
                const float v = tanhf(acc[i][j][r] + bias);
                h_out[(size_t)row * HH + col] = (__bf16)v;
            }
        }
    }
}

// out[b][o] = sum_h h[b][h] * W_out[o][h] + b_out[o]; one block per batch row.
__global__ __launch_bounds__(256) void rnn_out(
    const __bf16* __restrict__ h,      // [B][H] bf16
    const float*  __restrict__ W_out,  // [O][H] fp32
    const float*  __restrict__ b_out,  // [O]
    float* __restrict__ out)           // [B][O]
{
    const int b   = blockIdx.x;
    const int tid = threadIdx.x;
    __shared__ float red[OO][4];

    float hv[8];
#pragma unroll
    for (int e = 0; e < 8; ++e)
        hv[e] = (float)h[(size_t)b * HH + tid + e * 256];

#pragma unroll
    for (int o = 0; o < OO; ++o) {
        float s = 0.0f;
#pragma unroll
        for (int e = 0; e < 8; ++e)
            s += hv[e] * W_out[(size_t)o * HH + tid + e * 256];
        for (int off = 32; off; off >>= 1) s += __shfl_down(s, off);
        if ((tid & 63) == 0) red[o][tid >> 6] = s;
    }
    __syncthreads();
    if (tid < OO) {
        float s = red[tid][0] + red[tid][1] + red[tid][2] + red[tid][3];
        out[(size_t)b * OO + tid] = s + b_out[tid];
    }
}

extern "C" void kernel_launch(void* const* d_in, const int* in_sizes, int n_in,
                              void* d_out, int out_size, void* d_ws, size_t ws_size,
                              hipStream_t stream) {
    (void)in_sizes; (void)n_in; (void)out_size; (void)ws_size;

    const float* x     = (const float*)d_in[0];  // [256][128][512]
    const float* W_hx  = (const float*)d_in[1];  // [2048][512]
    const float* b_hx  = (const float*)d_in[2];  // [2048]
    const float* W_hh  = (const float*)d_in[3];  // [2048][2048]
    const float* b_hh  = (const float*)d_in[4];  // [2048]
    const float* W_out = (const float*)d_in[5];  // [10][2048]
    const float* b_out = (const float*)d_in[6];  // [10]
    float* out = (float*)d_out;

    char* ws = (char*)d_ws;
    __bf16* Whh_bf = (__bf16*)ws;                                            //  8 MB
    __bf16* Whx_bf = (__bf16*)(ws + (size_t)HH * HH * 2);                    //  2 MB
    __bf16* hbuf0  = (__bf16*)(ws + (size_t)HH * HH * 2 + (size_t)HH * II * 2);
    __bf16* hbuf1  = hbuf0 + (size_t)BB * HH;                                //  1 MB each

    cvt_f32_bf16<<<1024, 256, 0, stream>>>(W_hh, Whh_bf, HH * HH / 4);
    cvt_f32_bf16<<<512, 256, 0, stream>>>(W_hx, Whx_bf, HH * II / 4);

    dim3 sgrid(BB / 64, HH / 64);   // 4 x 32 = 128 blocks
    __bf16* hc = hbuf0;
    __bf16* hn = hbuf1;

    // t = 0: no hh branch, no b_hh (matches reference).
    rnn_step<<<sgrid, 256, 0, stream>>>(nullptr, x, 0, Whh_bf, Whx_bf, b_hx, b_hh, hc, 0);
    // t = 1 .. 126
    for (int t = 1; t <= SS - 2; ++t) {
        rnn_step<<<sgrid, 256, 0, stream>>>(hc, x, t, Whh_bf, Whx_bf, b_hx, b_hh, hn, 1);
        __bf16* tmp = hc; hc = hn; hn = tmp;
    }

    rnn_out<<<BB, 256, 0, stream>>>(hc, W_out, b_out, out);
}

// Round 3
// 4987.385 us; speedup vs baseline: 1.2097x; 1.2097x over previous
//
#include <hip/hip_runtime.h>
#include <hip/hip_bf16.h>

// VanillaRNN on MI355X — persistent cooperative kernel.
// h_t = tanh(x_t @ W_hx^T + h_{t-1} @ W_hh^T + b_hx + b_hh)  (hh term skipped at t=0)
// out = h_last @ W_out^T + b_out
//
// 256 blocks x 512 threads, 1 block/CU (128 KiB LDS = W_hh col-slice, staged once,
// XOR-swizzled). W_hx fragments in registers. h ping-pongs in ws; device-scope
// grid barrier between timesteps. bf16 MFMA 16x16x32, fp32 accum.

#define BB 256
#define SS 128
#define II 512
#define HH 2048
#define OO 10

#define NBLK 256
#define NTHR 512
#define MB 64            // batch rows per block
#define NB 32            // hidden cols per block
#define LDS_BYTES (NB * HH * 2)   // 131072

typedef __attribute__((ext_vector_type(8))) __bf16 bf16x8;
typedef __attribute__((ext_vector_type(4))) float f32x4;

__device__ __forceinline__ bf16x8 cvt8(float4 f0, float4 f1) {
    bf16x8 r;
    r[0] = (__bf16)f0.x; r[1] = (__bf16)f0.y; r[2] = (__bf16)f0.z; r[3] = (__bf16)f0.w;
    r[4] = (__bf16)f1.x; r[5] = (__bf16)f1.y; r[6] = (__bf16)f1.z; r[7] = (__bf16)f1.w;
    return r;
}

// Device-scope grid barrier: cumulative counter, release on arrive, acquire on exit.
// Spin is RELAXED (no repeated cache invalidates); one fence after exit.
// Bounded spin so a pathological schedule degrades to wrong-answer, not a hang.
__device__ __forceinline__ void grid_barrier(unsigned* cnt, unsigned target) {
    __syncthreads();                       // all waves done with this step (stores drained)
    if (threadIdx.x == 0) {
        __threadfence();                   // release: L2 writeback, writes visible at agent scope
        __hip_atomic_fetch_add(cnt, 1u, __ATOMIC_ACQ_REL, __HIP_MEMORY_SCOPE_AGENT);
        unsigned polls = 0;
        while (__hip_atomic_load(cnt, __ATOMIC_RELAXED, __HIP_MEMORY_SCOPE_AGENT) < target) {
            __builtin_amdgcn_s_sleep(4);
            if (++polls > (1u << 20)) break;   // ~0.2 s safety valve
        }
        __threadfence();                   // acquire: invalidate stale L1/L2 lines
    }
    __syncthreads();
}

extern "C" __global__ void __launch_bounds__(NTHR, 1) rnn_persist(
    const float* __restrict__ x,      // [B][S][I] fp32
    const float* __restrict__ Whh,    // [H][H] fp32
    const float* __restrict__ Whx,    // [H][I] fp32
    const float* __restrict__ bhx,    // [H]
    const float* __restrict__ bhh,    // [H]
    __bf16* __restrict__ hb0,         // [B][H] ping
    __bf16* __restrict__ hb1,         // [B][H] pong
    unsigned* __restrict__ cnt)       // grid-barrier counter (zeroed on stream)
{
    extern __shared__ __align__(16) char lds[];
    const int tid = threadIdx.x;
    const int bid = blockIdx.x;
    const int bi  = bid & 3;          // batch-row group 0..3
    const int bj  = bid >> 2;         // hidden-col group 0..63

    // ---- stage W_hh col-slice -> LDS (fp32 -> bf16, swizzled), once ----
    {
        const int col = tid >> 4;     // 0..31
        const int kc  = tid & 15;     // 0..15 -> k = kc*8 + k0
        const float* src = Whh + (size_t)(bj * NB + col) * HH + kc * 8;
        const unsigned base = (unsigned)col * (HH * 2) + (unsigned)kc * 16;
        const unsigned swz  = (unsigned)(col & 7) << 4;
#pragma unroll
        for (int k0 = 0; k0 < HH; k0 += 128) {
            float4 f0 = *reinterpret_cast<const float4*>(src + k0);
            float4 f1 = *reinterpret_cast<const float4*>(src + k0 + 4);
            *reinterpret_cast<bf16x8*>(lds + ((base + (unsigned)k0 * 2) ^ swz)) = cvt8(f0, f1);
        }
    }

    // ---- wave decomposition: 8 waves = 4 row x 2 col, 16x16 tiles ----
    const int lane = tid & 63;
    const int wid  = tid >> 6;        // 0..7
    const int wr   = wid >> 1;        // 0..3
    const int wn   = wid & 1;         // 0..1
    const int lr   = lane & 15;
    const int lk   = (lane >> 4) * 8; // contiguous-8 K offset
    const int arow = bi * MB + wr * 16 + lr;              // A-operand row (batch)
    const int ccol = bj * NB + wn * 16 + lr;              // output col (hidden)
    const unsigned braw = (unsigned)(wn * 16 + lr) * (HH * 2) + (unsigned)lk * 2;
    const unsigned bswz = (unsigned)(lr & 7) << 4;

    // ---- preload W_hx fragments (16 cols x K=512 per wave) into registers ----
    bf16x8 wx[16];
    {
        const float* p = Whx + (size_t)ccol * II + lk;
#pragma unroll
        for (int q = 0; q < 16; ++q) {
            float4 f0 = *reinterpret_cast<const float4*>(p + q * 32);
            float4 f1 = *reinterpret_cast<const float4*>(p + q * 32 + 4);
            wx[q] = cvt8(f0, f1);
        }
    }
    const float bx = bhx[ccol];
    const float bh = bhh[ccol];

    const float* xrow = x + (size_t)arow * SS * II + lk;
    const int drow0 = bi * MB + wr * 16 + 4 * (lane >> 4);  // D rows: drow0 + r

    __syncthreads();   // W_hh staging complete

    for (int s = 0; s < SS - 1; ++s) {
        const __bf16* hr = (s & 1) ? hb0 : hb1;
        __bf16*       hw = (s & 1) ? hb1 : hb0;

        f32x4 acc[4] = {};

        if (s > 0) {
            const __bf16* ap = hr + (size_t)arow * HH + lk;
            for (int kk = 0; kk < HH; kk += 256) {
#pragma unroll
                for (int j = 0; j < 8; ++j) {
                    const int k = kk + j * 32;
                    bf16x8 a = *reinterpret_cast<const bf16x8*>(ap + k);
                    bf16x8 b = *reinterpret_cast<const bf16x8*>(
                        lds + ((braw + (unsigned)k * 2) ^ bswz));
                    acc[j & 3] = __builtin_amdgcn_mfma_f32_16x16x32_bf16(a, b, acc[j & 3], 0, 0, 0);
                }
            }
        }

        // input-projection part (K=512), B-frags from registers
        {
            const float* xp = xrow + (size_t)s * II;
#pragma unroll
            for (int q = 0; q < 16; ++q) {
                float4 f0 = *reinterpret_cast<const float4*>(xp + q * 32);
                float4 f1 = *reinterpret_cast<const float4*>(xp + q * 32 + 4);
                acc[q & 3] = __builtin_amdgcn_mfma_f32_16x16x32_bf16(
                    cvt8(f0, f1), wx[q], acc[q & 3], 0, 0, 0);
            }
        }

        f32x4 r = acc[0] + acc[1] + acc[2] + acc[3];
        const float bias = bx + (s > 0 ? bh : 0.0f);
#pragma unroll
        for (int e = 0; e < 4; ++e) {
            hw[(size_t)(drow0 + e) * HH + ccol] = (__bf16)tanhf(r[e] + bias);
        }

        if (s < SS - 2) grid_barrier(cnt, (unsigned)(s + 1) * NBLK);
    }
}

// out[b][o] = sum_h h[b][h] * W_out[o][h] + b_out[o]; one block per batch row.
__global__ __launch_bounds__(256) void rnn_out(
    const __bf16* __restrict__ h, const float* __restrict__ W_out,
    const float* __restrict__ b_out, float* __restrict__ out)
{
    const int b = blockIdx.x;
    const int tid = threadIdx.x;
    __shared__ float red[OO][4];

    float hv[8];
#pragma unroll
    for (int e = 0; e < 8; ++e)
        hv[e] = (float)h[(size_t)b * HH + tid + e * 256];

#pragma unroll
    for (int o = 0; o < OO; ++o) {
        float s = 0.0f;
#pragma unroll
        for (int e = 0; e < 8; ++e)
            s += hv[e] * W_out[(size_t)o * HH + tid + e * 256];
        for (int off = 32; off; off >>= 1) s += __shfl_down(s, off);
        if ((tid & 63) == 0) red[o][tid >> 6] = s;
    }
    __syncthreads();
    if (tid < OO) {
        float s = red[tid][0] + red[tid][1] + red[tid][2] + red[tid][3];
        out[(size_t)b * OO + tid] = s + b_out[tid];
    }
}

extern "C" void kernel_launch(void* const* d_in, const int* in_sizes, int n_in,
                              void* d_out, int out_size, void* d_ws, size_t ws_size,
                              hipStream_t stream) {
    (void)in_sizes; (void)n_in; (void)out_size; (void)ws_size;

    const float* x     = (const float*)d_in[0];
    const float* W_hx  = (const float*)d_in[1];
    const float* b_hx  = (const float*)d_in[2];
    const float* W_hh  = (const float*)d_in[3];
    const float* b_hh  = (const float*)d_in[4];
    const float* W_out = (const float*)d_in[5];
    const float* b_out = (const float*)d_in[6];
    float* out = (float*)d_out;

    char* ws = (char*)d_ws;
    __bf16*  hb0 = (__bf16*)ws;                               // 1 MB
    __bf16*  hb1 = hb0 + (size_t)BB * HH;                     // 1 MB
    unsigned* cnt = (unsigned*)(ws + 2 * (size_t)BB * HH * 2);

    hipMemsetAsync(cnt, 0, sizeof(unsigned), stream);

    static bool attr_set = false;   // host-side, deterministic (same effect every call)
    if (!attr_set) {
        hipFuncSetAttribute(reinterpret_cast<const void*>(rnn_persist),
                            hipFuncAttributeMaxDynamicSharedMemorySize, LDS_BYTES);
        attr_set = true;
    }

    void* args[] = {(void*)&x, (void*)&W_hh, (void*)&W_hx, (void*)&b_hx,
                    (void*)&b_hh, (void*)&hb0, (void*)&hb1, (void*)&cnt};
    hipError_t e = hipLaunchCooperativeKernel(
        reinterpret_cast<const void*>(rnn_persist),
        dim3(NBLK), dim3(NTHR), args, LDS_BYTES, stream);
    if (e != hipSuccess) {
        // Fallback: plain launch. 128 KiB LDS -> 1 block/CU, grid == CU count,
        // so all blocks are co-resident; barrier spin has a timeout regardless.
        rnn_persist<<<dim3(NBLK), dim3(NTHR), LDS_BYTES, stream>>>(
            x, W_hh, W_hx, b_hx, b_hh, hb0, hb1, cnt);
    }

    // 127 steps: step s writes (s&1)?hb1:hb0; s=126 (even) -> hb0 holds h_last.
    rnn_out<<<BB, 256, 0, stream>>>(hb0, W_out, b_out, out);
}

// Round 4
// 4014.477 us; speedup vs baseline: 1.5029x; 1.2423x over previous
//
#include <hip/hip_runtime.h>
#include <hip/hip_bf16.h>

// VanillaRNN on MI355X — persistent cooperative kernel, fence-light barrier.
// h_t = tanh(x_t @ W_hx^T + h_{t-1} @ W_hh^T + b_hx + b_hh)  (hh term skipped at t=0)
// out = h_last @ W_out^T + b_out
//
// 256 blocks x 512 threads, 1 block/CU. W_hh col-slice (32 cols) in 128 KiB LDS,
// staged once, XOR-swizzled. W_hx fragments in registers. h ping-pongs in ws.
// Coherence protocol per step:
//   - h stores: agent-scope write-through (__hip_atomic_store ulong) -> never dirty L2
//   - release: s_waitcnt vmcnt(0) + one relaxed agent atomic-add per block
//   - acquire: one fence(acquire,"agent") per wave, EARLY (before spin) -> single
//     clustered L2 invalidate per step, no mid-step thrash; h reads stay L2-cached.
// MFMA operands swapped (A=W, B=h) so each lane's 4 outputs are 4 consecutive
// hidden cols of one batch row = one 8B contiguous agent store.

#define BB 256
#define SS 128
#define II 512
#define HH 2048
#define OO 10

#define NBLK 256
#define NTHR 512
#define LDS_BYTES (32 * HH * 2)   // 131072

typedef __attribute__((ext_vector_type(8))) __bf16 bf16x8;
typedef __attribute__((ext_vector_type(4))) float f32x4;

__device__ __forceinline__ bf16x8 cvt8(float4 f0, float4 f1) {
    bf16x8 r;
    r[0] = (__bf16)f0.x; r[1] = (__bf16)f0.y; r[2] = (__bf16)f0.z; r[3] = (__bf16)f0.w;
    r[4] = (__bf16)f1.x; r[5] = (__bf16)f1.y; r[6] = (__bf16)f1.z; r[7] = (__bf16)f1.w;
    return r;
}

extern "C" __global__ void __launch_bounds__(NTHR, 1) rnn_persist(
    const float* __restrict__ x,      // [B][S][I] fp32
    const float* __restrict__ Whh,    // [H][H] fp32
    const float* __restrict__ Whx,    // [H][I] fp32
    const float* __restrict__ bhx,    // [H]
    const float* __restrict__ bhh,    // [H]
    __bf16* __restrict__ hb0,         // [B][H] ping
    __bf16* __restrict__ hb1,         // [B][H] pong
    unsigned* __restrict__ cnt)       // grid-barrier counter (zeroed per launch)
{
    extern __shared__ __align__(16) char lds[];
    const int tid = threadIdx.x;
    const int bid = blockIdx.x;
    const int bi  = bid & 3;          // batch-row group 0..3   (XCD j hosts bi = j&3)
    const int bj  = bid >> 2;         // hidden-col group 0..63

    // ---- stage W_hh col-slice -> LDS (fp32 -> bf16, swizzled), once ----
    {
        const int col = tid >> 4;     // 0..31
        const int kc  = tid & 15;     // k = kc*8 + k0
        const float* src = Whh + (size_t)(bj * 32 + col) * HH + kc * 8;
        const unsigned base = (unsigned)col * (HH * 2) + (unsigned)kc * 16;
        const unsigned swz  = (unsigned)(col & 7) << 4;
#pragma unroll
        for (int k0 = 0; k0 < HH; k0 += 128) {
            float4 f0 = *reinterpret_cast<const float4*>(src + k0);
            float4 f1 = *reinterpret_cast<const float4*>(src + k0 + 4);
            *reinterpret_cast<bf16x8*>(lds + ((base + (unsigned)k0 * 2) ^ swz)) = cvt8(f0, f1);
        }
    }

    // ---- wave decomposition: 8 waves = 4 row-groups x 2 col-groups, 16x16 tiles ----
    const int lane = tid & 63;
    const int wid  = tid >> 6;
    const int wr   = wid >> 1;        // 0..3
    const int wn   = wid & 1;         // 0..1
    const int lr   = lane & 15;
    const int lk   = (lane >> 4) * 8; // contiguous-8 K offset
    const int brow = bi * 64 + wr * 16 + lr;          // batch row (B-operand / h-frag)
    const int hcol = bj * 32 + wn * 16 + lr;          // hidden col (A-operand / W-frag)
    const unsigned braw = (unsigned)(wn * 16 + lr) * (HH * 2) + (unsigned)lk * 2;
    const unsigned bswz = (unsigned)(lr & 7) << 4;

    // ---- preload W_hx fragments (K=512) into registers ----
    bf16x8 wx[16];
    {
        const float* p = Whx + (size_t)hcol * II + lk;
#pragma unroll
        for (int q = 0; q < 16; ++q) {
            float4 f0 = *reinterpret_cast<const float4*>(p + q * 32);
            float4 f1 = *reinterpret_cast<const float4*>(p + q * 32 + 4);
            wx[q] = cvt8(f0, f1);
        }
    }

    // ---- epilogue mapping: D(A=W,B=h): lane&15 = batch row, 4*(lane>>4)+e = col ----
    const int ecol0 = bj * 32 + wn * 16 + 4 * (lane >> 4);   // 4 consecutive cols
    const int erow  = bi * 64 + wr * 16 + (lane & 15);
    const float4 bx4 = *reinterpret_cast<const float4*>(bhx + ecol0);
    const float4 bh4 = *reinterpret_cast<const float4*>(bhh + ecol0);

    const float* xrow = x + (size_t)brow * SS * II + lk;

    __syncthreads();   // W_hh staging complete

    for (int s = 0; s < SS - 1; ++s) {
        const __bf16* hr = (s & 1) ? hb0 : hb1;
        __bf16*       hw = (s & 1) ? hb1 : hb0;

        // Early acquire: single clustered L2/L1 invalidate per step, BEFORE the
        // spin. Nothing is ever dirty in L2 (h stores are write-through), so
        // this is safe, and no stale h lines can re-enter before our reads.
        if (s > 0) __builtin_amdgcn_fence(__ATOMIC_ACQUIRE, "agent");

        f32x4 acc[4] = {};

        // ---- input-projection part (independent of h: overlaps barrier wait) ----
        {
            const float* xp = xrow + (size_t)s * II;
#pragma unroll
            for (int q = 0; q < 16; ++q) {
                float4 f0 = *reinterpret_cast<const float4*>(xp + q * 32);
                float4 f1 = *reinterpret_cast<const float4*>(xp + q * 32 + 4);
                acc[q & 3] = __builtin_amdgcn_mfma_f32_16x16x32_bf16(
                    wx[q], cvt8(f0, f1), acc[q & 3], 0, 0, 0);
            }
        }

        if (s > 0) {
            // ---- wait for barrier s-1 -> s ----
            if (tid == 0) {
                const unsigned target = (unsigned)s * NBLK;
                unsigned polls = 0;
                while (__hip_atomic_load(cnt, __ATOMIC_RELAXED,
                                         __HIP_MEMORY_SCOPE_AGENT) < target) {
                    __builtin_amdgcn_s_sleep(4);
                    if (++polls > (1u << 20)) break;   // no-hang safety valve
                }
            }
            __syncthreads();

            // ---- hh part: A = W_hh frag (LDS), B = h frag (global, L2-cached) ----
            const __bf16* bp = hr + (size_t)brow * HH + lk;
            for (int kk = 0; kk < HH; kk += 256) {
#pragma unroll
                for (int j = 0; j < 8; ++j) {
                    const int k = kk + j * 32;
                    bf16x8 hfrag = *reinterpret_cast<const bf16x8*>(bp + k);
                    bf16x8 wfrag = *reinterpret_cast<const bf16x8*>(
                        lds + ((braw + (unsigned)k * 2) ^ bswz));
                    acc[j & 3] = __builtin_amdgcn_mfma_f32_16x16x32_bf16(
                        wfrag, hfrag, acc[j & 3], 0, 0, 0);
                }
            }
        }

        // ---- epilogue: bias + tanh, pack 4 bf16, one 8B agent store per lane ----
        f32x4 r = acc[0] + acc[1] + acc[2] + acc[3];
        union { unsigned short u[4]; unsigned long long ll; } P;
#pragma unroll
        for (int e = 0; e < 4; ++e) {
            const float bias = ((const float*)&bx4)[e] +
                               (s > 0 ? ((const float*)&bh4)[e] : 0.0f);
            __bf16 v = (__bf16)tanhf(r[e] + bias);
            P.u[e] = __builtin_bit_cast(unsigned short, v);
        }
        __hip_atomic_store(
            reinterpret_cast<unsigned long long*>(hw + (size_t)erow * HH + ecol0),
            P.ll, __ATOMIC_RELAXED, __HIP_MEMORY_SCOPE_AGENT);

        // ---- arrive at barrier s -> s+1 ----
        if (s < SS - 2) {
            asm volatile("s_waitcnt vmcnt(0)" ::: "memory");  // stores acked at IF
            __syncthreads();
            if (tid == 0)
                __hip_atomic_fetch_add(cnt, 1u, __ATOMIC_RELAXED,
                                       __HIP_MEMORY_SCOPE_AGENT);
        }
    }
}

// out[b][o] = sum_h h[b][h] * W_out[o][h] + b_out[o]; one block per batch row.
__global__ __launch_bounds__(256) void rnn_out(
    const __bf16* __restrict__ h, const float* __restrict__ W_out,
    const float* __restrict__ b_out, float* __restrict__ out)
{
    const int b = blockIdx.x;
    const int tid = threadIdx.x;
    __shared__ float red[OO][4];

    float hv[8];
#pragma unroll
    for (int e = 0; e < 8; ++e)
        hv[e] = (float)h[(size_t)b * HH + tid + e * 256];

#pragma unroll
    for (int o = 0; o < OO; ++o) {
        float s = 0.0f;
#pragma unroll
        for (int e = 0; e < 8; ++e)
            s += hv[e] * W_out[(size_t)o * HH + tid + e * 256];
        for (int off = 32; off; off >>= 1) s += __shfl_down(s, off);
        if ((tid & 63) == 0) red[o][tid >> 6] = s;
    }
    __syncthreads();
    if (tid < OO) {
        float s = red[tid][0] + red[tid][1] + red[tid][2] + red[tid][3];
        out[(size_t)b * OO + tid] = s + b_out[tid];
    }
}

extern "C" void kernel_launch(void* const* d_in, const int* in_sizes, int n_in,
                              void* d_out, int out_size, void* d_ws, size_t ws_size,
                              hipStream_t stream) {
    (void)in_sizes; (void)n_in; (void)out_size; (void)ws_size;

    const float* x     = (const float*)d_in[0];
    const float* W_hx  = (const float*)d_in[1];
    const float* b_hx  = (const float*)d_in[2];
    const float* W_hh  = (const float*)d_in[3];
    const float* b_hh  = (const float*)d_in[4];
    const float* W_out = (const float*)d_in[5];
    const float* b_out = (const float*)d_in[6];
    float* out = (float*)d_out;

    char* ws = (char*)d_ws;
    __bf16*  hb0 = (__bf16*)ws;                               // 1 MB
    __bf16*  hb1 = hb0 + (size_t)BB * HH;                     // 1 MB
    unsigned* cnt = (unsigned*)(ws + 2 * (size_t)BB * HH * 2);

    hipMemsetAsync(cnt, 0, sizeof(unsigned), stream);

    static bool attr_set = false;   // host-side one-time setup (same effect every call)
    if (!attr_set) {
        hipFuncSetAttribute(reinterpret_cast<const void*>(rnn_persist),
                            hipFuncAttributeMaxDynamicSharedMemorySize, LDS_BYTES);
        attr_set = true;
    }

    void* args[] = {(void*)&x, (void*)&W_hh, (void*)&W_hx, (void*)&b_hx,
                    (void*)&b_hh, (void*)&hb0, (void*)&hb1, (void*)&cnt};
    hipError_t e = hipLaunchCooperativeKernel(
        reinterpret_cast<const void*>(rnn_persist),
        dim3(NBLK), dim3(NTHR), args, LDS_BYTES, stream);
    if (e != hipSuccess) {
        // Fallback: plain launch. 128 KiB LDS -> 1 block/CU, grid == CU count,
        // so all blocks co-resident; barrier spin has a timeout regardless.
        rnn_persist<<<dim3(NBLK), dim3(NTHR), LDS_BYTES, stream>>>(
            x, W_hh, W_hx, b_hx, b_hh, hb0, hb1, cnt);
    }

    // 127 steps: step s writes (s&1)?hb1:hb0; s=126 (even) -> hb0 holds h_last.
    rnn_out<<<BB, 256, 0, stream>>>(hb0, W_out, b_out, out);
}

// Round 5
// 2569.245 us; speedup vs baseline: 2.3483x; 1.5625x over previous
//
#include <hip/hip_runtime.h>
#include <hip/hip_bf16.h>

// VanillaRNN on MI355X — persistent cooperative kernel, XCD-local h exchange.
// h_t = tanh(x_t @ W_hx^T + h_{t-1} @ W_hh^T + b_hx + b_hh)  (hh term skipped at t=0)
// out = h_last @ W_out^T + b_out
//
// Runtime self-organization: grp = XCC_ID (32 batch rows), slot = per-XCD
// atomic counter (64 hidden cols). All producers/consumers of a given h row
// share one XCD -> plain stores (dirty in shared L2) + agent-scope relaxed
// atomic loads (L1-bypassing) give coherence with NO fences, NO L2 invalidates.
// W_hh slice entirely in VGPRs (8 waves, K-split-4, 32 frags = 128 regs/lane).
// LDS only for the cross-wave K-reduction (padded, conflict-free).
// Per-XCD 32-way barrier; x-projection MFMAs issued before the barrier wait.

#define BB 256
#define SS 128
#define II 512
#define HH 2048
#define OO 10

#define NTHR 512
#define NBLK 256
#define LDS_RED (6 * 64 * 20 * 4)   // 30720 B reduce scratch, 20-float lane stride

typedef __attribute__((ext_vector_type(8))) __bf16 bf16x8;
typedef __attribute__((ext_vector_type(4))) __bf16 bf16x4;
typedef __attribute__((ext_vector_type(4))) float f32x4;
typedef unsigned long long u64;

__device__ __forceinline__ bf16x8 cvt8(float4 f0, float4 f1) {
    bf16x8 r;
    r[0] = (__bf16)f0.x; r[1] = (__bf16)f0.y; r[2] = (__bf16)f0.z; r[3] = (__bf16)f0.w;
    r[4] = (__bf16)f1.x; r[5] = (__bf16)f1.y; r[6] = (__bf16)f1.z; r[7] = (__bf16)f1.w;
    return r;
}
__device__ __forceinline__ bf16x8 mk8(u64 a, u64 b) {
    union { u64 u[2]; bf16x8 v; } t; t.u[0] = a; t.u[1] = b; return t.v;
}

__global__ __launch_bounds__(256) void cvt_f32_bf16(const float* __restrict__ in,
                                                    __bf16* __restrict__ out, int n4) {
    int stride = gridDim.x * blockDim.x;
    for (int i = blockIdx.x * blockDim.x + threadIdx.x; i < n4; i += stride) {
        float4 v = reinterpret_cast<const float4*>(in)[i];
        bf16x4 o;
        o[0] = (__bf16)v.x; o[1] = (__bf16)v.y; o[2] = (__bf16)v.z; o[3] = (__bf16)v.w;
        *reinterpret_cast<bf16x4*>(out + 4 * (size_t)i) = o;
    }
}

#define AGLD(p) __hip_atomic_load((p), __ATOMIC_RELAXED, __HIP_MEMORY_SCOPE_AGENT)

#define HHLOAD(BUF, KCB)                                                        \
    _Pragma("unroll")                                                           \
    for (int kc = 0; kc < 4; ++kc) {                                            \
        BUF[kc][0][0] = AGLD(hq0 + (KCB + kc) * 8);                             \
        BUF[kc][0][1] = AGLD(hq0 + (KCB + kc) * 8 + 1);                         \
        BUF[kc][1][0] = AGLD(hq1 + (KCB + kc) * 8);                             \
        BUF[kc][1][1] = AGLD(hq1 + (KCB + kc) * 8 + 1);                         \
    }

#define HHMFMA(BUF, KCB)                                                        \
    _Pragma("unroll")                                                           \
    for (int kc = 0; kc < 4; ++kc)                                              \
        _Pragma("unroll")                                                       \
        for (int cf = 0; cf < 2; ++cf)                                          \
            _Pragma("unroll")                                                   \
            for (int rf = 0; rf < 2; ++rf)                                      \
                acc[cf][rf] = __builtin_amdgcn_mfma_f32_16x16x32_bf16(          \
                    whh[cf][KCB + kc], mk8(BUF[kc][rf][0], BUF[kc][rf][1]),     \
                    acc[cf][rf], 0, 0, 0);

extern "C" __global__ void __launch_bounds__(NTHR, 2) rnn_persist(
    const float*  __restrict__ x,      // [B][S][I] fp32
    const __bf16* __restrict__ Whh,    // [H][H] bf16 prepacked
    const __bf16* __restrict__ Whx,    // [H][I] bf16 prepacked
    const float*  __restrict__ bhx,    // [H]
    const float*  __restrict__ bhh,    // [H]
    __bf16* __restrict__ hb0,          // [B][H] ping
    __bf16* __restrict__ hb1,          // [B][H] pong
    unsigned* __restrict__ ctrs)       // [1024] zeroed: slot[g]=g*64, bar[g]=512+g*64
{
    extern __shared__ __align__(16) float red[];
    const int tid = threadIdx.x;

    unsigned xcc;
    asm volatile("s_getreg_b32 %0, hwreg(HW_REG_XCC_ID)" : "=s"(xcc));
    const int grp = (int)(xcc & 7u);

    __shared__ unsigned slot_sh;
    if (tid == 0)
        slot_sh = __hip_atomic_fetch_add(ctrs + grp * 64, 1u, __ATOMIC_RELAXED,
                                         __HIP_MEMORY_SCOPE_AGENT);
    __syncthreads();
    const int slot = (int)(slot_sh & 31u);

    const int lane = tid & 63;
    const int wid  = tid >> 6;
    const int kh   = wid >> 1;          // 0..3  K-split
    const int cg   = wid & 1;           // 0..1  col-group
    const int lq   = lane >> 4;         // 0..3
    const int lr   = lane & 15;
    const int colbase = slot * 64 + cg * 32;   // hidden cols [colbase, +32)
    const int rowbase = grp * 32;              // batch rows  [rowbase, +32)

    // ---- W_hh fragments -> registers (persistent): col=colbase+cf*16+lr, K span kh*512.. ----
    bf16x8 whh[2][16];
#pragma unroll
    for (int cf = 0; cf < 2; ++cf) {
        const __bf16* wp = Whh + (size_t)(colbase + cf * 16 + lr) * HH + kh * 512 + lq * 8;
#pragma unroll
        for (int kc = 0; kc < 16; ++kc)
            whh[cf][kc] = *reinterpret_cast<const bf16x8*>(wp + kc * 32);
    }
    // ---- biases (used by kh==0 waves in epilogue) ----
    f32x4 biasS[2], bias0[2];
#pragma unroll
    for (int cf = 0; cf < 2; ++cf) {
        const int c0 = colbase + cf * 16 + 4 * lq;
        float4 bx = *reinterpret_cast<const float4*>(bhx + c0);
        float4 bh = *reinterpret_cast<const float4*>(bhh + c0);
        bias0[cf][0] = bx.x; bias0[cf][1] = bx.y; bias0[cf][2] = bx.z; bias0[cf][3] = bx.w;
        biasS[cf][0] = bx.x + bh.x; biasS[cf][1] = bx.y + bh.y;
        biasS[cf][2] = bx.z + bh.z; biasS[cf][3] = bx.w + bh.w;
    }

    unsigned* bar = ctrs + 512 + grp * 64;

    for (int s = 0; s < SS - 1; ++s) {
        const __bf16* hr = (s & 1) ? hb0 : hb1;
        __bf16*       hw = (s & 1) ? hb1 : hb0;

        f32x4 acc[2][2] = {};   // [cf][rf]

        // ---- x-projection (independent of h; hides barrier wait) ----
        {
            bf16x8 wxf[2][4], xf[2][4];
#pragma unroll
            for (int cf = 0; cf < 2; ++cf) {
                const __bf16* wp = Whx + (size_t)(colbase + cf * 16 + lr) * II + kh * 128 + lq * 8;
#pragma unroll
                for (int kc = 0; kc < 4; ++kc)
                    wxf[cf][kc] = *reinterpret_cast<const bf16x8*>(wp + kc * 32);
            }
#pragma unroll
            for (int rf = 0; rf < 2; ++rf) {
                const float* xp = x + (size_t)(rowbase + rf * 16 + lr) * (SS * II)
                                  + (size_t)s * II + kh * 128 + lq * 8;
#pragma unroll
                for (int kc = 0; kc < 4; ++kc) {
                    float4 f0 = *reinterpret_cast<const float4*>(xp + kc * 32);
                    float4 f1 = *reinterpret_cast<const float4*>(xp + kc * 32 + 4);
                    xf[rf][kc] = cvt8(f0, f1);
                }
            }
#pragma unroll
            for (int kc = 0; kc < 4; ++kc)
#pragma unroll
                for (int cf = 0; cf < 2; ++cf)
#pragma unroll
                    for (int rf = 0; rf < 2; ++rf)
                        acc[cf][rf] = __builtin_amdgcn_mfma_f32_16x16x32_bf16(
                            wxf[cf][kc], xf[rf][kc], acc[cf][rf], 0, 0, 0);
        }

        if (s > 0) {
            // ---- per-XCD barrier wait (arrivals of step s-1) ----
            if (tid == 0) {
                const unsigned target = (unsigned)s * 32u;
                unsigned polls = 0;
                while (AGLD(bar) < target) {
                    __builtin_amdgcn_s_sleep(1);
                    if (++polls > (1u << 20)) break;   // no-hang safety valve
                }
            }
            __syncthreads();

            // ---- hh part: A = W_hh (VGPR), B = h frags via agent loads (L2-hot) ----
            const u64* hq0 = reinterpret_cast<const u64*>(
                hr + (size_t)(rowbase + lr) * HH + kh * 512 + lq * 8);
            const u64* hq1 = reinterpret_cast<const u64*>(
                hr + (size_t)(rowbase + 16 + lr) * HH + kh * 512 + lq * 8);
            u64 hA[4][2][2], hB[4][2][2];
            HHLOAD(hA, 0)
            HHLOAD(hB, 4)
            HHMFMA(hA, 0)
            HHLOAD(hA, 8)
            HHMFMA(hB, 4)
            HHLOAD(hB, 12)
            HHMFMA(hA, 8)
            HHMFMA(hB, 12)
        }

        // ---- cross-wave K-reduction via LDS (padded: 20-float lane stride) ----
        if (kh > 0) {
            float* wp_ = red + ((size_t)(cg * 3 + kh - 1) * 64 + lane) * 20;
#pragma unroll
            for (int cf = 0; cf < 2; ++cf)
#pragma unroll
                for (int rf = 0; rf < 2; ++rf)
                    *reinterpret_cast<f32x4*>(wp_ + (cf * 2 + rf) * 4) = acc[cf][rf];
        }
        __syncthreads();   // SB1: partials visible
        if (kh == 0) {
#pragma unroll
            for (int w = 0; w < 3; ++w) {
                const float* rp = red + ((size_t)(cg * 3 + w) * 64 + lane) * 20;
#pragma unroll
                for (int cf = 0; cf < 2; ++cf)
#pragma unroll
                    for (int rf = 0; rf < 2; ++rf)
                        acc[cf][rf] += *reinterpret_cast<const f32x4*>(rp + (cf * 2 + rf) * 4);
            }
            // ---- epilogue: bias + tanh, one 8B store per (cf,rf) per lane ----
#pragma unroll
            for (int cf = 0; cf < 2; ++cf) {
                const f32x4 b = (s > 0) ? biasS[cf] : bias0[cf];
#pragma unroll
                for (int rf = 0; rf < 2; ++rf) {
                    union { unsigned short u[4]; u64 ll; } P;
#pragma unroll
                    for (int e = 0; e < 4; ++e) {
                        __bf16 v = (__bf16)tanhf(acc[cf][rf][e] + b[e]);
                        P.u[e] = __builtin_bit_cast(unsigned short, v);
                    }
                    *reinterpret_cast<u64*>(
                        hw + (size_t)(rowbase + rf * 16 + lr) * HH + colbase + cf * 16 + 4 * lq)
                        = P.ll;
                }
            }
            asm volatile("s_waitcnt vmcnt(0)" ::: "memory");   // stores in L2
        }
        __syncthreads();   // SB2: all stores of this step complete
        if (s < SS - 2 && tid == 0)
            __hip_atomic_fetch_add(bar, 1u, __ATOMIC_RELAXED, __HIP_MEMORY_SCOPE_AGENT);
    }
}

// out[b][o] = sum_h h[b][h] * W_out[o][h] + b_out[o]; one block per batch row.
__global__ __launch_bounds__(256) void rnn_out(
    const __bf16* __restrict__ h, const float* __restrict__ W_out,
    const float* __restrict__ b_out, float* __restrict__ out)
{
    const int b = blockIdx.x;
    const int tid = threadIdx.x;
    __shared__ float red[OO][4];

    float hv[8];
#pragma unroll
    for (int e = 0; e < 8; ++e)
        hv[e] = (float)h[(size_t)b * HH + tid + e * 256];

#pragma unroll
    for (int o = 0; o < OO; ++o) {
        float s = 0.0f;
#pragma unroll
        for (int e = 0; e < 8; ++e)
            s += hv[e] * W_out[(size_t)o * HH + tid + e * 256];
        for (int off = 32; off; off >>= 1) s += __shfl_down(s, off);
        if ((tid & 63) == 0) red[o][tid >> 6] = s;
    }
    __syncthreads();
    if (tid < OO) {
        float s = red[tid][0] + red[tid][1] + red[tid][2] + red[tid][3];
        out[(size_t)b * OO + tid] = s + b_out[tid];
    }
}

extern "C" void kernel_launch(void* const* d_in, const int* in_sizes, int n_in,
                              void* d_out, int out_size, void* d_ws, size_t ws_size,
                              hipStream_t stream) {
    (void)in_sizes; (void)n_in; (void)out_size; (void)ws_size;

    const float* x     = (const float*)d_in[0];
    const float* W_hx  = (const float*)d_in[1];
    const float* b_hx  = (const float*)d_in[2];
    const float* W_hh  = (const float*)d_in[3];
    const float* b_hh  = (const float*)d_in[4];
    const float* W_out = (const float*)d_in[5];
    const float* b_out = (const float*)d_in[6];
    float* out = (float*)d_out;

    char* ws = (char*)d_ws;
    __bf16*   hb0    = (__bf16*)ws;                                   // 1 MB
    __bf16*   hb1    = hb0 + (size_t)BB * HH;                         // 1 MB
    unsigned* ctrs   = (unsigned*)(ws + 2 * (size_t)BB * HH * 2);     // 4 KB
    __bf16*   Whh_bf = (__bf16*)(ws + 2 * (size_t)BB * HH * 2 + 4096);// 8 MB
    __bf16*   Whx_bf = Whh_bf + (size_t)HH * HH;                      // 2 MB

    hipMemsetAsync(ctrs, 0, 4096, stream);
    cvt_f32_bf16<<<1024, 256, 0, stream>>>(W_hh, Whh_bf, HH * HH / 4);
    cvt_f32_bf16<<<512, 256, 0, stream>>>(W_hx, Whx_bf, HH * II / 4);

    void* args[] = {(void*)&x, (void*)&Whh_bf, (void*)&Whx_bf, (void*)&b_hx,
                    (void*)&b_hh, (void*)&hb0, (void*)&hb1, (void*)&ctrs};
    hipError_t e = hipLaunchCooperativeKernel(
        reinterpret_cast<const void*>(rnn_persist),
        dim3(NBLK), dim3(NTHR), args, LDS_RED, stream);
    if (e != hipSuccess) {
        // Fallback: plain launch. VGPR>128 forces 1 block/CU, grid == CU count,
        // so all blocks co-resident; barrier spin has a timeout regardless.
        rnn_persist<<<dim3(NBLK), dim3(NTHR), LDS_RED, stream>>>(
            x, Whh_bf, Whx_bf, b_hx, b_hh, hb0, hb1, ctrs);
    }

    // 127 steps: step s writes (s&1)?hb1:hb0; s=126 (even) -> hb0 holds h_last.
    rnn_out<<<BB, 256, 0, stream>>>(hb0, W_out, b_out, out);
}

// Round 6
// 1704.967 us; speedup vs baseline: 3.5386x; 1.5069x over previous
//
#include <hip/hip_runtime.h>
#include <hip/hip_bf16.h>

// VanillaRNN on MI355X — persistent cooperative kernel, XCD-local h exchange.
// h_t = tanh(x_t @ W_hx^T + h_{t-1} @ W_hh^T + b_hx + b_hh)  (hh term skipped at t=0)
// out = h_last @ W_out^T + b_out
//
// grp = XCC_ID (32 batch rows), slot = per-XCD atomic (64 hidden cols).
// Producers/consumers of each h row share one XCD: plain stores (dirty in that
// XCD's L2) + sc0 loads (L1-bypass, TA-coalesced) give coherence, no fences.
// W_hh slice in VGPRs (8 waves, K-split-4, 32 frags = 128 regs/lane).
// launch_bounds(512,1): 256-VGPR cap so whh actually stays in registers.
// h frags: inline-asm global_load_dwordx4 sc0, 2-chunk pipeline, explicit
// vmcnt(0)+sched_barrier before each MFMA cluster.

#define BB 256
#define SS 128
#define II 512
#define HH 2048
#define OO 10

#define NTHR 512
#define NBLK 256
#define LDS_RED (6 * 64 * 20 * 4)   // 30720 B reduce scratch, 20-float lane stride

typedef __attribute__((ext_vector_type(8))) __bf16 bf16x8;
typedef __attribute__((ext_vector_type(4))) __bf16 bf16x4;
typedef __attribute__((ext_vector_type(4))) float f32x4;
typedef unsigned long long u64;

__device__ __forceinline__ bf16x8 cvt8(float4 f0, float4 f1) {
    bf16x8 r;
    r[0] = (__bf16)f0.x; r[1] = (__bf16)f0.y; r[2] = (__bf16)f0.z; r[3] = (__bf16)f0.w;
    r[4] = (__bf16)f1.x; r[5] = (__bf16)f1.y; r[6] = (__bf16)f1.z; r[7] = (__bf16)f1.w;
    return r;
}

__global__ __launch_bounds__(256) void cvt_f32_bf16(const float* __restrict__ in,
                                                    __bf16* __restrict__ out, int n4) {
    int stride = gridDim.x * blockDim.x;
    for (int i = blockIdx.x * blockDim.x + threadIdx.x; i < n4; i += stride) {
        float4 v = reinterpret_cast<const float4*>(in)[i];
        bf16x4 o;
        o[0] = (__bf16)v.x; o[1] = (__bf16)v.y; o[2] = (__bf16)v.z; o[3] = (__bf16)v.w;
        *reinterpret_cast<bf16x4*>(out + 4 * (size_t)i) = o;
    }
}

#define AGLD(p) __hip_atomic_load((p), __ATOMIC_RELAXED, __HIP_MEMORY_SCOPE_AGENT)

// sc0 = agent-coherent load: bypasses (invalidates) L1, hits dirty L2 lines from
// other CUs on the same XCD, fully TA-coalesced (unlike atomic loads).
#define LD1(dst, base, off)                                                     \
    asm volatile("global_load_dwordx4 %0, %1, off offset:" #off " sc0"          \
                 : "=&v"(dst) : "v"(base));
// One chunk = 4 kc x 2 rows = 8 dwordx4 (32 VGPR). Offsets are kc*64 bytes.
#define LOADC(BUF, O0, O1, O2, O3)                                              \
    LD1(BUF[0], p0, O0) LD1(BUF[1], p1, O0)                                     \
    LD1(BUF[2], p0, O1) LD1(BUF[3], p1, O1)                                     \
    LD1(BUF[4], p0, O2) LD1(BUF[5], p1, O2)                                     \
    LD1(BUF[6], p0, O3) LD1(BUF[7], p1, O3)

#define WAIT0                                                                   \
    asm volatile("s_waitcnt vmcnt(0)" ::: "memory");                            \
    __builtin_amdgcn_sched_barrier(0);

#define MFMAC(BUF, KCB)                                                         \
    _Pragma("unroll")                                                           \
    for (int kc = 0; kc < 4; ++kc)                                              \
        _Pragma("unroll")                                                       \
        for (int cf = 0; cf < 2; ++cf)                                          \
            _Pragma("unroll")                                                   \
            for (int rf = 0; rf < 2; ++rf)                                      \
                acc[cf][rf] = __builtin_amdgcn_mfma_f32_16x16x32_bf16(          \
                    whh[cf][KCB + kc], BUF[kc * 2 + rf], acc[cf][rf], 0, 0, 0);

extern "C" __global__ void __launch_bounds__(NTHR, 1) rnn_persist(
    const float*  __restrict__ x,      // [B][S][I] fp32
    const __bf16* __restrict__ Whh,    // [H][H] bf16 prepacked
    const __bf16* __restrict__ Whx,    // [H][I] bf16 prepacked
    const float*  __restrict__ bhx,    // [H]
    const float*  __restrict__ bhh,    // [H]
    __bf16* __restrict__ hb0,          // [B][H] ping
    __bf16* __restrict__ hb1,          // [B][H] pong
    unsigned* __restrict__ ctrs)       // [1024] zeroed: slot[g]=g*64, bar[g]=512+g*64
{
    extern __shared__ __align__(16) float red[];
    const int tid = threadIdx.x;

    unsigned xcc;
    asm volatile("s_getreg_b32 %0, hwreg(HW_REG_XCC_ID)" : "=s"(xcc));
    const int grp = (int)(xcc & 7u);

    __shared__ unsigned slot_sh;
    if (tid == 0)
        slot_sh = __hip_atomic_fetch_add(ctrs + grp * 64, 1u, __ATOMIC_RELAXED,
                                         __HIP_MEMORY_SCOPE_AGENT);
    __syncthreads();
    const int slot = (int)(slot_sh & 31u);

    const int lane = tid & 63;
    const int wid  = tid >> 6;
    const int kh   = wid >> 1;          // 0..3  K-split
    const int cg   = wid & 1;           // 0..1  col-group
    const int lq   = lane >> 4;         // 0..3
    const int lr   = lane & 15;
    const int colbase = slot * 64 + cg * 32;   // hidden cols [colbase, +32)
    const int rowbase = grp * 32;              // batch rows  [rowbase, +32)

    // ---- W_hh fragments -> registers (persistent, 128 VGPR) ----
    bf16x8 whh[2][16];
#pragma unroll
    for (int cf = 0; cf < 2; ++cf) {
        const __bf16* wp = Whh + (size_t)(colbase + cf * 16 + lr) * HH + kh * 512 + lq * 8;
#pragma unroll
        for (int kc = 0; kc < 16; ++kc)
            whh[cf][kc] = *reinterpret_cast<const bf16x8*>(wp + kc * 32);
    }
    // ---- biases (used by kh==0 waves in epilogue) ----
    f32x4 biasS[2], bias0[2];
#pragma unroll
    for (int cf = 0; cf < 2; ++cf) {
        const int c0 = colbase + cf * 16 + 4 * lq;
        float4 bx = *reinterpret_cast<const float4*>(bhx + c0);
        float4 bh = *reinterpret_cast<const float4*>(bhh + c0);
        bias0[cf][0] = bx.x; bias0[cf][1] = bx.y; bias0[cf][2] = bx.z; bias0[cf][3] = bx.w;
        biasS[cf][0] = bx.x + bh.x; biasS[cf][1] = bx.y + bh.y;
        biasS[cf][2] = bx.z + bh.z; biasS[cf][3] = bx.w + bh.w;
    }

    unsigned* bar = ctrs + 512 + grp * 64;

    for (int s = 0; s < SS - 1; ++s) {
        const __bf16* hr = (s & 1) ? hb0 : hb1;
        __bf16*       hw = (s & 1) ? hb1 : hb0;

        f32x4 acc[2][2] = {};   // [cf][rf]

        // ---- x-projection (independent of h; hides barrier wait) ----
        {
            bf16x8 wxf[2][4], xf[2][4];
#pragma unroll
            for (int cf = 0; cf < 2; ++cf) {
                const __bf16* wp = Whx + (size_t)(colbase + cf * 16 + lr) * II + kh * 128 + lq * 8;
#pragma unroll
                for (int kc = 0; kc < 4; ++kc)
                    wxf[cf][kc] = *reinterpret_cast<const bf16x8*>(wp + kc * 32);
            }
#pragma unroll
            for (int rf = 0; rf < 2; ++rf) {
                const float* xp = x + (size_t)(rowbase + rf * 16 + lr) * (SS * II)
                                  + (size_t)s * II + kh * 128 + lq * 8;
#pragma unroll
                for (int kc = 0; kc < 4; ++kc) {
                    float4 f0 = *reinterpret_cast<const float4*>(xp + kc * 32);
                    float4 f1 = *reinterpret_cast<const float4*>(xp + kc * 32 + 4);
                    xf[rf][kc] = cvt8(f0, f1);
                }
            }
#pragma unroll
            for (int kc = 0; kc < 4; ++kc)
#pragma unroll
                for (int cf = 0; cf < 2; ++cf)
#pragma unroll
                    for (int rf = 0; rf < 2; ++rf)
                        acc[cf][rf] = __builtin_amdgcn_mfma_f32_16x16x32_bf16(
                            wxf[cf][kc], xf[rf][kc], acc[cf][rf], 0, 0, 0);
        }

        if (s > 0) {
            // ---- per-XCD barrier wait (arrivals of step s-1) ----
            if (tid == 0) {
                const unsigned target = (unsigned)s * 32u;
                unsigned polls = 0;
                while (AGLD(bar) < target) {
                    __builtin_amdgcn_s_sleep(1);
                    if (++polls > (1u << 20)) break;   // no-hang safety valve
                }
            }
            __syncthreads();

            // ---- hh part: A = W_hh (VGPR), B = h frags via coalesced sc0 loads ----
            const char* p0 = (const char*)(hr + (size_t)(rowbase + lr) * HH + kh * 512 + lq * 8);
            const char* p1 = (const char*)(hr + (size_t)(rowbase + 16 + lr) * HH + kh * 512 + lq * 8);
            bf16x8 bufA[8], bufB[8];
            WAIT0                                   // make vmcnt state exact
            LOADC(bufA, 0, 64, 128, 192)
            WAIT0                                   // bufA ready
            LOADC(bufB, 256, 320, 384, 448)         // in flight under MFMA A
            MFMAC(bufA, 0)
            WAIT0                                   // bufB ready
            LOADC(bufA, 512, 576, 640, 704)
            MFMAC(bufB, 4)
            WAIT0
            LOADC(bufB, 768, 832, 896, 960)
            MFMAC(bufA, 8)
            WAIT0
            MFMAC(bufB, 12)
        }

        // ---- cross-wave K-reduction via LDS (padded: 20-float lane stride) ----
        if (kh > 0) {
            float* wp_ = red + ((size_t)(cg * 3 + kh - 1) * 64 + lane) * 20;
#pragma unroll
            for (int cf = 0; cf < 2; ++cf)
#pragma unroll
                for (int rf = 0; rf < 2; ++rf)
                    *reinterpret_cast<f32x4*>(wp_ + (cf * 2 + rf) * 4) = acc[cf][rf];
        }
        __syncthreads();   // SB1: partials visible
        if (kh == 0) {
#pragma unroll
            for (int w = 0; w < 3; ++w) {
                const float* rp = red + ((size_t)(cg * 3 + w) * 64 + lane) * 20;
#pragma unroll
                for (int cf = 0; cf < 2; ++cf)
#pragma unroll
                    for (int rf = 0; rf < 2; ++rf)
                        acc[cf][rf] += *reinterpret_cast<const f32x4*>(rp + (cf * 2 + rf) * 4);
            }
            // ---- epilogue: bias + tanh, one 8B store per (cf,rf) per lane ----
#pragma unroll
            for (int cf = 0; cf < 2; ++cf) {
                const f32x4 b = (s > 0) ? biasS[cf] : bias0[cf];
#pragma unroll
                for (int rf = 0; rf < 2; ++rf) {
                    union { unsigned short u[4]; u64 ll; } P;
#pragma unroll
                    for (int e = 0; e < 4; ++e) {
                        __bf16 v = (__bf16)tanhf(acc[cf][rf][e] + b[e]);
                        P.u[e] = __builtin_bit_cast(unsigned short, v);
                    }
                    *reinterpret_cast<u64*>(
                        hw + (size_t)(rowbase + rf * 16 + lr) * HH + colbase + cf * 16 + 4 * lq)
                        = P.ll;
                }
            }
            asm volatile("s_waitcnt vmcnt(0)" ::: "memory");   // stores in L2
        }
        __syncthreads();   // SB2: all stores of this step complete
        if (s < SS - 2 && tid == 0)
            __hip_atomic_fetch_add(bar, 1u, __ATOMIC_RELAXED, __HIP_MEMORY_SCOPE_AGENT);
    }
}

// out[b][o] = sum_h h[b][h] * W_out[o][h] + b_out[o]; one block per batch row.
__global__ __launch_bounds__(256) void rnn_out(
    const __bf16* __restrict__ h, const float* __restrict__ W_out,
    const float* __restrict__ b_out, float* __restrict__ out)
{
    const int b = blockIdx.x;
    const int tid = threadIdx.x;
    __shared__ float red[OO][4];

    float hv[8];
#pragma unroll
    for (int e = 0; e < 8; ++e)
        hv[e] = (float)h[(size_t)b * HH + tid + e * 256];

#pragma unroll
    for (int o = 0; o < OO; ++o) {
        float s = 0.0f;
#pragma unroll
        for (int e = 0; e < 8; ++e)
            s += hv[e] * W_out[(size_t)o * HH + tid + e * 256];
        for (int off = 32; off; off >>= 1) s += __shfl_down(s, off);
        if ((tid & 63) == 0) red[o][tid >> 6] = s;
    }
    __syncthreads();
    if (tid < OO) {
        float s = red[tid][0] + red[tid][1] + red[tid][2] + red[tid][3];
        out[(size_t)b * OO + tid] = s + b_out[tid];
    }
}

extern "C" void kernel_launch(void* const* d_in, const int* in_sizes, int n_in,
                              void* d_out, int out_size, void* d_ws, size_t ws_size,
                              hipStream_t stream) {
    (void)in_sizes; (void)n_in; (void)out_size; (void)ws_size;

    const float* x     = (const float*)d_in[0];
    const float* W_hx  = (const float*)d_in[1];
    const float* b_hx  = (const float*)d_in[2];
    const float* W_hh  = (const float*)d_in[3];
    const float* b_hh  = (const float*)d_in[4];
    const float* W_out = (const float*)d_in[5];
    const float* b_out = (const float*)d_in[6];
    float* out = (float*)d_out;

    char* ws = (char*)d_ws;
    __bf16*   hb0    = (__bf16*)ws;                                   // 1 MB
    __bf16*   hb1    = hb0 + (size_t)BB * HH;                         // 1 MB
    unsigned* ctrs   = (unsigned*)(ws + 2 * (size_t)BB * HH * 2);     // 4 KB
    __bf16*   Whh_bf = (__bf16*)(ws + 2 * (size_t)BB * HH * 2 + 4096);// 8 MB
    __bf16*   Whx_bf = Whh_bf + (size_t)HH * HH;                      // 2 MB

    hipMemsetAsync(ctrs, 0, 4096, stream);
    cvt_f32_bf16<<<1024, 256, 0, stream>>>(W_hh, Whh_bf, HH * HH / 4);
    cvt_f32_bf16<<<512, 256, 0, stream>>>(W_hx, Whx_bf, HH * II / 4);

    void* args[] = {(void*)&x, (void*)&Whh_bf, (void*)&Whx_bf, (void*)&b_hx,
                    (void*)&b_hh, (void*)&hb0, (void*)&hb1, (void*)&ctrs};
    hipError_t e = hipLaunchCooperativeKernel(
        reinterpret_cast<const void*>(rnn_persist),
        dim3(NBLK), dim3(NTHR), args, LDS_RED, stream);
    if (e != hipSuccess) {
        // Fallback: plain launch. ~240 VGPR -> 1 block/CU, grid == CU count,
        // so all blocks co-resident; barrier spin has a timeout regardless.
        rnn_persist<<<dim3(NBLK), dim3(NTHR), LDS_RED, stream>>>(
            x, Whh_bf, Whx_bf, b_hx, b_hh, hb0, hb1, ctrs);
    }

    // 127 steps: step s writes (s&1)?hb1:hb0; s=126 (even) -> hb0 holds h_last.
    rnn_out<<<BB, 256, 0, stream>>>(hb0, W_out, b_out, out);
}